// Round 16
// baseline (1289.859 us; speedup 1.0000x reference)
//
#include <hip/hip_runtime.h>
#include <stdint.h>

#define TT  1024
#define BB  512
#define OBS 128
#define HH  64
#define AA  18
#define RT  (TT*BB)
#define OFF_L ((size_t)BB*HH)
#define OFF_V (OFF_L + (size_t)TT*BB*AA)

typedef __attribute__((ext_vector_type(8))) short bf16x8;
typedef __attribute__((ext_vector_type(4))) float f32x4;
typedef __attribute__((ext_vector_type(4))) unsigned int u32x4;

__device__ __forceinline__ float fast_rcp(float x){ return __builtin_amdgcn_rcpf(x); }
__device__ __forceinline__ float sigm(float x){ return fast_rcp(1.f + __expf(-x)); }
__device__ __forceinline__ float tanh_(float x){ return 1.f - 2.f*fast_rcp(1.f + __expf(2.f*x)); }

__device__ __forceinline__ unsigned bf16_rne(float f){
    unsigned u = __float_as_uint(f);
    return (u + 0x7FFFu + ((u>>16)&1u)) >> 16;
}
__device__ __forceinline__ unsigned pk_bf16(float lo, float hi){
    unsigned d;
    asm("v_cvt_pk_bf16_f32 %0, %1, %2" : "=v"(d) : "v"(lo), "v"(hi));
    return d;
}

#define RAWBAR()  do { asm volatile("s_waitcnt lgkmcnt(0)" ::: "memory"); \
                       __builtin_amdgcn_s_barrier(); } while(0)
#define FULLBAR() do { asm volatile("s_waitcnt vmcnt(0) lgkmcnt(0)" ::: "memory"); \
                       __builtin_amdgcn_s_barrier(); } while(0)

// ---- mask-dtype detection: any uint32 word >1 => byte-packed bool ----
__global__ void detect_mask(const uint32_t* __restrict__ m, uint32_t* __restrict__ flag)
{
    const int n_words = (TT * BB) / 4;
    uint32_t acc = 0;
    for (int i = blockIdx.x * blockDim.x + threadIdx.x; i < n_words;
         i += gridDim.x * blockDim.x)
        acc |= (m[i] > 1u) ? 1u : 0u;
    if (acc) flag[0] = 1u;
}

// ===== mega: stem-producer + GRU-consumer + heads, one kernel ============
// 32 blocks x 8 waves. Waves 0-3: GRU (recur9 structure, gi from LDS ring).
// Waves 4-5: stem producers (z[s+2], gi[s+1], x glds ring). Waves 6-7:
// heads (y/logits for t'=s-1, parity split). One raw barrier per step.
#define ZSTR 70

__global__ __launch_bounds__(512, 1)
void mega(const float* __restrict__ x,
          const void* __restrict__ mask_raw,
          const uint32_t* __restrict__ mflag,
          const float* __restrict__ ic,
          const float* __restrict__ W1, const float* __restrict__ b1,
          const float* __restrict__ Wi, const float* __restrict__ bi,
          const float* __restrict__ Wh, const float* __restrict__ bhn,
          const float* __restrict__ W2, const float* __restrict__ b2,
          const float* __restrict__ Wl, const float* __restrict__ bl,
          const float* __restrict__ Wv, const float* __restrict__ bv,
          float* __restrict__ out)
{
    const int blk = blockIdx.x;      // 0..31, 16 chains each
    const int tid = threadIdx.x;     // 0..511
    const int w   = tid >> 6;        // 0..7
    const int l   = tid & 63;
    const int a   = l & 15;
    const int q   = l >> 4;

    __shared__ float    x_lds[4][16*OBS];   // x ring (linear, glds dest) 32KB
    __shared__ float    gi_ring[4][3072];   // [slot][tau*256+l*4+e]      48KB
    __shared__ float    zs[2][16*ZSTR];     // z exchange (producers)      9KB
    __shared__ float    yb[2][16*ZSTR];     // per-heads-wave y buffer     9KB
    __shared__ float    h_lds[2][64][17];   //                            8.7KB
    __shared__ uint32_t mbits[TT];          //                             4KB

    // ---- common: mask bits + h(0-) ----
    if (mflag[0] != 0) {
        const uint8_t* m8 = (const uint8_t*)mask_raw;
        for (int t0 = w*4; t0 < TT; t0 += 32) {
            const int tt = t0 + q;
            const uint64_t bal = __ballot(m8[(size_t)tt*BB + blk*16 + a] != 0);
            if (l < 4) mbits[t0 + l] = (uint32_t)((bal >> (16*l)) & 0xFFFFu);
        }
    } else {
        const int32_t* m32 = (const int32_t*)mask_raw;
        for (int t0 = w*4; t0 < TT; t0 += 32) {
            const int tt = t0 + q;
            const uint64_t bal = __ballot(m32[(size_t)tt*BB + blk*16 + a] != 0);
            if (l < 4) mbits[t0 + l] = (uint32_t)((bal >> (16*l)) & 0xFFFFu);
        }
    }
    for (int i = tid; i < 16*64; i += 512) {
        const int c = i & 15, d = i >> 4;
        h_lds[0][d][c] = ic[(blk*16 + c)*HH + d];
    }
    __syncthreads();   // B0

    if (w < 4) {
        // ================= GRU consumer =================
        const int dw = w*16 + a;
        bf16x8 Bf[3][2];
        #pragma unroll
        for (int g = 0; g < 3; ++g) {
            const int colb = g*64 + dw;
            #pragma unroll
            for (int s2 = 0; s2 < 2; ++s2) {
                u32x4 pk;
                #pragma unroll
                for (int j2 = 0; j2 < 4; ++j2) {
                    const int k0 = s2*32 + q*8 + j2*2;
                    pk[j2] = bf16_rne(Wh[(size_t)k0*192 + colb])
                           | (bf16_rne(Wh[(size_t)(k0+1)*192 + colb]) << 16);
                }
                Bf[g][s2] = __builtin_bit_cast(bf16x8, pk);
            }
        }
        u32x4 icA[2];
        #pragma unroll
        for (int s2 = 0; s2 < 2; ++s2)
            #pragma unroll
            for (int j2 = 0; j2 < 4; ++j2) {
                const int d0 = s2*32 + q*8 + j2*2;
                icA[s2][j2] = bf16_rne(ic[(blk*16 + a)*HH + d0])
                            | (bf16_rne(ic[(blk*16 + a)*HH + d0 + 1]) << 16);
            }
        float ic_c[4], h_reg[4];
        #pragma unroll
        for (int e = 0; e < 4; ++e) {
            ic_c[e]  = ic[(blk*16 + q*4 + e)*HH + dw];
            h_reg[e] = ic_c[e];
        }
        const float bhnv = bhn[dw];
        const f32x4 Cn = {bhnv, bhnv, bhnv, bhnv};

        FULLBAR();  // B0.5
        FULLBAR();  // B1
        FULLBAR();  // B2

        for (int s = 0; s < TT; ++s) {
            const int p = s & 1;
            const float* rg = &gi_ring[s & 3][0];
            const f32x4 cur0 = *(const f32x4*)(rg + (0*4 + w)*256 + l*4);
            const f32x4 cur1 = *(const f32x4*)(rg + (1*4 + w)*256 + l*4);
            const f32x4 cur2 = *(const f32x4*)(rg + (2*4 + w)*256 + l*4);
            const uint32_t mb = mbits[s];
            const bool mA = (mb >> a) & 1;
            u32x4 Apk0, Apk1;
            #pragma unroll
            for (int j2 = 0; j2 < 4; ++j2) {
                const int d0 = q*8 + j2*2;
                const unsigned r0 = pk_bf16(h_lds[p][d0][a],    h_lds[p][d0+1][a]);
                const unsigned r1 = pk_bf16(h_lds[p][32+d0][a], h_lds[p][32+d0+1][a]);
                Apk0[j2] = mA ? icA[0][j2] : r0;
                Apk1[j2] = mA ? icA[1][j2] : r1;
            }
            const bf16x8 A0 = __builtin_bit_cast(bf16x8, Apk0);
            const bf16x8 A1 = __builtin_bit_cast(bf16x8, Apk1);
            f32x4 Dr = __builtin_amdgcn_mfma_f32_16x16x32_bf16(A0, Bf[0][0], cur0, 0,0,0);
            Dr       = __builtin_amdgcn_mfma_f32_16x16x32_bf16(A1, Bf[0][1], Dr,   0,0,0);
            f32x4 Dz = __builtin_amdgcn_mfma_f32_16x16x32_bf16(A0, Bf[1][0], cur1, 0,0,0);
            Dz       = __builtin_amdgcn_mfma_f32_16x16x32_bf16(A1, Bf[1][1], Dz,   0,0,0);
            f32x4 Dn = __builtin_amdgcn_mfma_f32_16x16x32_bf16(A0, Bf[2][0], Cn,   0,0,0);
            Dn       = __builtin_amdgcn_mfma_f32_16x16x32_bf16(A1, Bf[2][1], Dn,   0,0,0);
            #pragma unroll
            for (int e = 0; e < 4; ++e) {
                const bool me   = (mb >> (q*4 + e)) & 1;
                const float he  = me ? ic_c[e] : h_reg[e];
                const float r   = sigm(Dr[e]);
                const float u   = sigm(Dz[e]);
                const float n   = tanh_(fmaf(r, Dn[e], cur2[e]));
                const float hn  = fmaf(u, he - n, n);
                h_reg[e] = hn;
                h_lds[p ^ 1][dw][q*4 + e] = hn;
            }
            RAWBAR();
        }
        #pragma unroll
        for (int e = 0; e < 4; ++e)
            out[(size_t)(blk*16 + q*4 + e)*HH + dw] = h_reg[e];

    } else if (w < 6) {
        // ================= stem producer =================
        const int pw = w - 4;
        bf16x8 W1f[2][4];                 // local nt = pw*2+ln
        float  b1v[2];
        #pragma unroll
        for (int ln = 0; ln < 2; ++ln) {
            const int col = (pw*2 + ln)*16 + a;
            b1v[ln] = b1[col];
            #pragma unroll
            for (int kf = 0; kf < 4; ++kf) {
                u32x4 pk;
                #pragma unroll
                for (int j2 = 0; j2 < 4; ++j2) {
                    const int k0 = kf*32 + q*8 + 2*j2;
                    pk[j2] = bf16_rne(W1[(size_t)k0*HH + col])
                           | (bf16_rne(W1[(size_t)(k0+1)*HH + col]) << 16);
                }
                W1f[ln][kf] = __builtin_bit_cast(bf16x8, pk);
            }
        }
        bf16x8 Wif[6][2];                 // taus pw*6 .. pw*6+5
        float  biv[6];
        #pragma unroll
        for (int lt = 0; lt < 6; ++lt) {
            const int col = (pw*6 + lt)*16 + a;
            biv[lt] = bi[col];
            #pragma unroll
            for (int s2 = 0; s2 < 2; ++s2) {
                u32x4 pk;
                #pragma unroll
                for (int j2 = 0; j2 < 4; ++j2) {
                    const int k0 = s2*32 + q*8 + 2*j2;
                    pk[j2] = bf16_rne(Wi[(size_t)k0*192 + col])
                           | (bf16_rne(Wi[(size_t)(k0+1)*192 + col]) << 16);
                }
                Wif[lt][s2] = __builtin_bit_cast(bf16x8, pk);
            }
        }

        // stage x[t_] half (insts i = pw*4..pw*4+3) into x_lds[slot]
        auto stage_x = [&](int t_, int slot) {
            #pragma unroll
            for (int i = 0; i < 4; ++i) {
                const int ii = pw*4 + i;
                const float* gsrc = x + ((size_t)t_*BB + blk*16)*OBS + ii*256 + l*4;
                __builtin_amdgcn_global_load_lds(
                    (const __attribute__((address_space(1))) void*)gsrc,
                    (__attribute__((address_space(3))) void*)
                        ((char*)&x_lds[slot][0] + ii*1024), 16, 0, 0);
            }
        };
        // z[t_] (this wave's 2 n-tiles) from x_lds[xslot] -> zs[zslot]
        auto make_z = [&](int xslot, int zslot) {
            bf16x8 Axf[4];
            #pragma unroll
            for (int kf = 0; kf < 4; ++kf) {
                const float4 v0 = *(const float4*)&x_lds[xslot][a*OBS + kf*32 + q*8];
                const float4 v1 = *(const float4*)&x_lds[xslot][a*OBS + kf*32 + q*8 + 4];
                u32x4 pk;
                pk[0] = pk_bf16(v0.x, v0.y); pk[1] = pk_bf16(v0.z, v0.w);
                pk[2] = pk_bf16(v1.x, v1.y); pk[3] = pk_bf16(v1.z, v1.w);
                Axf[kf] = __builtin_bit_cast(bf16x8, pk);
            }
            #pragma unroll
            for (int ln = 0; ln < 2; ++ln) {
                f32x4 D = {b1v[ln], b1v[ln], b1v[ln], b1v[ln]};
                #pragma unroll
                for (int kf = 0; kf < 4; ++kf)
                    D = __builtin_amdgcn_mfma_f32_16x16x32_bf16(Axf[kf], W1f[ln][kf], D, 0,0,0);
                #pragma unroll
                for (int e = 0; e < 4; ++e)
                    zs[zslot][(q*4 + e)*ZSTR + (pw*2 + ln)*16 + a] = fmaxf(D[e], 0.f);
            }
        };
        // gi[t_] (this wave's 6 taus) from zs[zslot] -> gi_ring[rslot]
        auto make_gi = [&](int zslot, int rslot) {
            bf16x8 Az[2];
            #pragma unroll
            for (int s2 = 0; s2 < 2; ++s2) {
                u32x4 pk;
                #pragma unroll
                for (int j2 = 0; j2 < 4; ++j2) {
                    const float2 f = *(const float2*)&zs[zslot][a*ZSTR + s2*32 + q*8 + 2*j2];
                    pk[j2] = pk_bf16(f.x, f.y);
                }
                Az[s2] = __builtin_bit_cast(bf16x8, pk);
            }
            #pragma unroll
            for (int lt = 0; lt < 6; ++lt) {
                f32x4 D = {biv[lt], biv[lt], biv[lt], biv[lt]};
                D = __builtin_amdgcn_mfma_f32_16x16x32_bf16(Az[0], Wif[lt][0], D, 0,0,0);
                D = __builtin_amdgcn_mfma_f32_16x16x32_bf16(Az[1], Wif[lt][1], D, 0,0,0);
                *(f32x4*)&gi_ring[rslot][(pw*6 + lt)*256 + l*4] = D;
            }
        };

        // prologue: x[0..3]; z[0],z[1]; gi[0]
        stage_x(0, 0); stage_x(1, 1); stage_x(2, 2); stage_x(3, 3);
        FULLBAR();  // B0.5: x[0..3] landed (both halves)
        make_z(0, 0);
        make_z(1, 1);
        FULLBAR();  // B1: zs[0], zs[1] ready
        make_gi(0, 0);
        FULLBAR();  // B2: ring[0] ready

        for (int s = 0; s < TT; ++s) {
            if (s + 2 < TT) {
                asm volatile("s_waitcnt vmcnt(0)" ::: "memory");  // x[s+2] landed
                if (s + 4 < TT) stage_x(s + 4, (s + 4) & 3);
                make_z((s + 2) & 3, (s + 2) & 1);
            }
            if (s + 1 < TT) make_gi((s + 1) & 1, (s + 1) & 3);
            RAWBAR();
        }

    } else {
        // ================= heads =================
        const int hw = w - 6;            // parity handled: t' & 1 == hw
        bf16x8 W2f[4][2];
        float  b2v[4];
        #pragma unroll
        for (int nt = 0; nt < 4; ++nt) {
            const int col = nt*16 + a;
            b2v[nt] = b2[col];
            #pragma unroll
            for (int s2 = 0; s2 < 2; ++s2) {
                u32x4 pk;
                #pragma unroll
                for (int j2 = 0; j2 < 4; ++j2) {
                    const int k0 = s2*32 + q*8 + 2*j2;
                    pk[j2] = bf16_rne(W2[(size_t)k0*HH + col])
                           | (bf16_rne(W2[(size_t)(k0+1)*HH + col]) << 16);
                }
                W2f[nt][s2] = __builtin_bit_cast(bf16x8, pk);
            }
        }
        bf16x8 Wlf[2][2];
        float  blv[2];
        #pragma unroll
        for (int tt2 = 0; tt2 < 2; ++tt2) {
            #pragma unroll
            for (int s2 = 0; s2 < 2; ++s2) {
                u32x4 pk;
                #pragma unroll
                for (int j2 = 0; j2 < 4; ++j2) {
                    const int k0 = s2*32 + q*8 + 2*j2;
                    unsigned lo = 0, hi = 0;
                    if (tt2 == 0) {
                        lo = bf16_rne(Wl[(size_t)k0*AA + a]);
                        hi = bf16_rne(Wl[(size_t)(k0+1)*AA + a]);
                    } else if (a < 2) {
                        lo = bf16_rne(Wl[(size_t)k0*AA + 16 + a]);
                        hi = bf16_rne(Wl[(size_t)(k0+1)*AA + 16 + a]);
                    } else if (a == 2) {
                        lo = bf16_rne(Wv[k0]);
                        hi = bf16_rne(Wv[k0+1]);
                    }
                    pk[j2] = lo | (hi << 16);
                }
                Wlf[tt2][s2] = __builtin_bit_cast(bf16x8, pk);
            }
        }
        blv[0] = bl[a];
        blv[1] = (a < 2) ? bl[16 + a] : (a == 2 ? bv[0] : 0.f);

        auto heads_step = [&](int t_) {
            const int hp = (t_ + 1) & 1;   // h(t_) parity slot
            u32x4 Ah0, Ah1;
            #pragma unroll
            for (int j2 = 0; j2 < 4; ++j2) {
                const int d0 = q*8 + 2*j2;
                Ah0[j2] = pk_bf16(h_lds[hp][d0][a],    h_lds[hp][d0+1][a]);
                Ah1[j2] = pk_bf16(h_lds[hp][32+d0][a], h_lds[hp][32+d0+1][a]);
            }
            const bf16x8 H0 = __builtin_bit_cast(bf16x8, Ah0);
            const bf16x8 H1 = __builtin_bit_cast(bf16x8, Ah1);
            #pragma unroll
            for (int nt = 0; nt < 4; ++nt) {
                f32x4 D = {b2v[nt], b2v[nt], b2v[nt], b2v[nt]};
                D = __builtin_amdgcn_mfma_f32_16x16x32_bf16(H0, W2f[nt][0], D, 0,0,0);
                D = __builtin_amdgcn_mfma_f32_16x16x32_bf16(H1, W2f[nt][1], D, 0,0,0);
                #pragma unroll
                for (int e = 0; e < 4; ++e)
                    yb[hw][(q*4 + e)*ZSTR + nt*16 + a] = fmaxf(D[e], 0.f);
            }
            bf16x8 Ay[2];
            #pragma unroll
            for (int s2 = 0; s2 < 2; ++s2) {
                u32x4 pk;
                #pragma unroll
                for (int j2 = 0; j2 < 4; ++j2) {
                    const float2 f = *(const float2*)&yb[hw][a*ZSTR + s2*32 + q*8 + 2*j2];
                    pk[j2] = pk_bf16(f.x, f.y);
                }
                Ay[s2] = __builtin_bit_cast(bf16x8, pk);
            }
            f32x4 D0 = {blv[0], blv[0], blv[0], blv[0]};
            D0 = __builtin_amdgcn_mfma_f32_16x16x32_bf16(Ay[0], Wlf[0][0], D0, 0,0,0);
            D0 = __builtin_amdgcn_mfma_f32_16x16x32_bf16(Ay[1], Wlf[0][1], D0, 0,0,0);
            f32x4 D1 = {blv[1], blv[1], blv[1], blv[1]};
            D1 = __builtin_amdgcn_mfma_f32_16x16x32_bf16(Ay[0], Wlf[1][0], D1, 0,0,0);
            D1 = __builtin_amdgcn_mfma_f32_16x16x32_bf16(Ay[1], Wlf[1][1], D1, 0,0,0);
            #pragma unroll
            for (int e = 0; e < 4; ++e)
                out[OFF_L + ((size_t)t_*BB + blk*16 + q*4 + e)*AA + a] = D0[e];
            if (a < 2) {
                #pragma unroll
                for (int e = 0; e < 4; ++e)
                    out[OFF_L + ((size_t)t_*BB + blk*16 + q*4 + e)*AA + 16 + a] = D1[e];
            } else if (a == 2) {
                #pragma unroll
                for (int e = 0; e < 4; ++e)
                    out[OFF_V + (size_t)t_*BB + blk*16 + q*4 + e] = D1[e];
            }
        };

        FULLBAR();  // B0.5
        FULLBAR();  // B1
        FULLBAR();  // B2

        for (int s = 0; s < TT; ++s) {
            if (s >= 1 && ((s - 1) & 1) == hw) heads_step(s - 1);
            RAWBAR();
        }
        if (hw == ((TT - 1) & 1)) heads_step(TT - 1);
    }
}

extern "C" void kernel_launch(void* const* d_in, const int* in_sizes, int n_in,
                              void* d_out, int out_size, void* d_ws, size_t ws_size,
                              hipStream_t stream) {
    const float* x    = (const float*)d_in[0];
    const void*  mask = (const void*) d_in[1];
    const float* ic   = (const float*)d_in[2];
    const float* W1   = (const float*)d_in[3];
    const float* b1   = (const float*)d_in[4];
    const float* Wi   = (const float*)d_in[5];
    const float* bi   = (const float*)d_in[6];
    const float* Wh   = (const float*)d_in[7];
    const float* bhn  = (const float*)d_in[8];
    const float* W2   = (const float*)d_in[9];
    const float* b2   = (const float*)d_in[10];
    const float* Wl   = (const float*)d_in[11];
    const float* bl   = (const float*)d_in[12];
    const float* Wv   = (const float*)d_in[13];
    const float* bv   = (const float*)d_in[14];
    float* out = (float*)d_out;

    uint32_t* flag = (uint32_t*)d_ws;
    hipMemsetAsync(flag, 0, sizeof(uint32_t), stream);
    detect_mask<<<64, 256, 0, stream>>>((const uint32_t*)mask, flag);
    mega<<<32, 512, 0, stream>>>(x, mask, flag, ic, W1, b1, Wi, bi, Wh, bhn,
                                 W2, b2, Wl, bl, Wv, bv, out);
}